// Round 1
// baseline (228.877 us; speedup 1.0000x reference)
//
#include <hip/hip_runtime.h>

#define NN 2048
#define DIMM 256
#define HEADS 8
#define HEAD_DIM 32
#define EXPH 16
#define E_EDGES 32768
#define VDIM 512          // EXPH*HEAD_DIM
#define PW 1024           // P row width: [q 256 | k*scale 256 | vv 512]
#define SCALE_F 0.17677669529663687f
#define MASKV -1.0e9f
#define MAXD 128

// ---------- edge-index dtype detection (int32 vs int64) ----------
__global__ void detect_kernel(const int* __restrict__ ei32, int* __restrict__ flag) {
    __shared__ int nz;
    if (threadIdx.x == 0) nz = 0;
    __syncthreads();
    if (ei32[2 * threadIdx.x + 1] != 0) atomicAdd(&nz, 1);
    __syncthreads();
    if (threadIdx.x == 0) flag[0] = (nz == 0) ? 1 : 0;  // 1 => int64
}

__device__ __forceinline__ int load_edge(const int* __restrict__ ei32, int is64, int idx) {
    return is64 ? ei32[2 * idx] : ei32[idx];  // little-endian low word holds value (< 2^31)
}

// ---------- projections: P[n][0:256]=x@Wq^T ; [256:512]=x@Wk^T*SCALE ; [512:1024]=x@Wv^T+edges@Wev^T
__global__ __launch_bounds__(256) void proj_kernel(
    const float* __restrict__ x, const float* __restrict__ edges,
    const float* __restrict__ Wq, const float* __restrict__ Wk,
    const float* __restrict__ Wv, const float* __restrict__ Wev,
    float* __restrict__ P)
{
    __shared__ float As[16][64];
    __shared__ float Bs[16][64];
    int t = threadIdx.x;
    int rowT = blockIdx.x * 64;
    int jb = blockIdx.y;
    int colT = jb * 64;

    const float* W; int wbase; int nseg = 1;
    if (jb < 4)      { W = Wq; wbase = colT; }
    else if (jb < 8) { W = Wk; wbase = colT - 256; }
    else             { W = Wv; wbase = colT - 512; nseg = 2; }

    int tm = t & 15, tn = t >> 4;
    float acc[4][4];
    #pragma unroll
    for (int i = 0; i < 4; i++)
        #pragma unroll
        for (int j = 0; j < 4; j++) acc[i][j] = 0.f;

    for (int seg = 0; seg < nseg; ++seg) {
        const float* A  = (seg == 0) ? x : edges;
        const float* Wm = (seg == 0) ? W : Wev;
        for (int k0 = 0; k0 < DIMM; k0 += 16) {
            int lr = t >> 2;
            int lk = (t & 3) * 4;
            float4 av = *(const float4*)(A + (size_t)(rowT + lr) * DIMM + k0 + lk);
            As[lk + 0][lr] = av.x; As[lk + 1][lr] = av.y;
            As[lk + 2][lr] = av.z; As[lk + 3][lr] = av.w;
            float4 bv = *(const float4*)(Wm + (size_t)(wbase + lr) * DIMM + k0 + lk);
            Bs[lk + 0][lr] = bv.x; Bs[lk + 1][lr] = bv.y;
            Bs[lk + 2][lr] = bv.z; Bs[lk + 3][lr] = bv.w;
            __syncthreads();
            #pragma unroll
            for (int kk = 0; kk < 16; kk++) {
                float4 a4 = *(const float4*)&As[kk][tm * 4];
                float4 b4 = *(const float4*)&Bs[kk][tn * 4];
                float am[4] = {a4.x, a4.y, a4.z, a4.w};
                float bm[4] = {b4.x, b4.y, b4.z, b4.w};
                #pragma unroll
                for (int i = 0; i < 4; i++)
                    #pragma unroll
                    for (int j = 0; j < 4; j++) acc[i][j] += am[i] * bm[j];
            }
            __syncthreads();
        }
    }
    float sc = (jb >= 4 && jb < 8) ? SCALE_F : 1.0f;
    #pragma unroll
    for (int i = 0; i < 4; i++) {
        int r = rowT + tm * 4 + i;
        #pragma unroll
        for (int j = 0; j < 4; j++)
            P[(size_t)r * PW + colT + tn * 4 + j] = acc[i][j] * sc;
    }
}

// ---------- M_e = sum_h MASKV * Wexp[e,h] ----------
__global__ void me_kernel(const float* __restrict__ Wexp, float* __restrict__ M) {
    int e = threadIdx.x;
    if (e < EXPH) {
        float s = 0.f;
        for (int h = 0; h < HEADS; h++) s += MASKV * Wexp[e * HEADS + h];
        M[e] = s;
    }
}

// ---------- colsum[j] = sum_n vv[n][j]  (deterministic serial-per-column) ----------
__global__ __launch_bounds__(256) void colsum_kernel(const float* __restrict__ P, float* __restrict__ colsum) {
    int j = blockIdx.x * 256 + threadIdx.x;  // 0..511
    float s = 0.f;
    for (int n = 0; n < NN; n++) s += P[(size_t)n * PW + 512 + j];
    colsum[j] = s;
}

// ---------- per-edge expanded attention values a[p][e] ----------
__global__ __launch_bounds__(256) void edgea_kernel(
    const int* __restrict__ ei32, const int* __restrict__ flag,
    const float* __restrict__ P, const float* __restrict__ Wexp,
    float* __restrict__ aArr)
{
    __shared__ float ewS[32][8];
    __shared__ float WexpS[EXPH * HEADS];
    int t = threadIdx.x;
    if (t < EXPH * HEADS) WexpS[t] = Wexp[t];
    int is64 = flag[0];
    int pl = t >> 3;
    int h  = t & 7;
    int p  = blockIdx.x * 32 + pl;
    int src = load_edge(ei32, is64, p);
    int dst = load_edge(ei32, is64, E_EDGES + p);
    const float4* qr = (const float4*)(P + (size_t)src * PW + h * 32);
    const float4* kr = (const float4*)(P + (size_t)dst * PW + 256 + h * 32);
    float s = 0.f;
    #pragma unroll
    for (int i = 0; i < 8; i++) {
        float4 a = qr[i], b = kr[i];
        s += a.x * b.x + a.y * b.y + a.z * b.z + a.w * b.w;
    }
    ewS[pl][h] = s;
    __syncthreads();
    #pragma unroll
    for (int r = 0; r < 2; r++) {
        int idx = t + r * 256;
        int pe = idx >> 4, e = idx & 15;
        float a = 0.f;
        #pragma unroll
        for (int hh = 0; hh < HEADS; hh++) a += ewS[pe][hh] * WexpS[e * HEADS + hh];
        aArr[(size_t)(blockIdx.x * 32 + pe) * EXPH + e] = a;
    }
}

// ---------- CSR build ----------
__global__ void hist_kernel(const int* __restrict__ ei32, const int* __restrict__ flag, int* __restrict__ deg) {
    int p = blockIdx.x * 256 + threadIdx.x;
    int is64 = flag[0];
    if (p < E_EDGES) atomicAdd(&deg[load_edge(ei32, is64, p)], 1);
}

__global__ __launch_bounds__(256) void scan_kernel(const int* __restrict__ deg, int* __restrict__ offs) {
    __shared__ int part[256];
    __shared__ int pref[257];
    int t = threadIdx.x;
    int base = t * 8;
    int s = 0;
    for (int i = 0; i < 8; i++) s += deg[base + i];
    part[t] = s;
    __syncthreads();
    if (t == 0) {
        int r = 0;
        for (int i = 0; i < 256; i++) { pref[i] = r; r += part[i]; }
        pref[256] = r;
    }
    __syncthreads();
    int run = pref[t];
    for (int i = 0; i < 8; i++) { offs[base + i] = run; run += deg[base + i]; }
    if (t == 0) offs[NN] = pref[256];
}

__global__ void fill_kernel(const int* __restrict__ ei32, const int* __restrict__ flag,
                            const int* __restrict__ offs, int* __restrict__ cursor,
                            int* __restrict__ edst, int* __restrict__ eid) {
    int p = blockIdx.x * 256 + threadIdx.x;
    int is64 = flag[0];
    if (p < E_EDGES) {
        int s = load_edge(ei32, is64, p);
        int pos = offs[s] + atomicAdd(&cursor[s], 1);
        edst[pos] = load_edge(ei32, is64, E_EDGES + p);
        eid[pos]  = p;
    }
}

// ---------- main: per-node softmax + Laplacian apply ----------
__global__ __launch_bounds__(256) void laplacian_kernel(
    const int* __restrict__ offs, const int* __restrict__ edst, const int* __restrict__ eid,
    const float* __restrict__ aArr, const float* __restrict__ Mbuf,
    const float* __restrict__ colsum, const float* __restrict__ P,
    float* __restrict__ out2)
{
    __shared__ int dstS[MAXD], idS[MAXD], liveS[MAXD];
    __shared__ float aS[MAXD][EXPH];
    __shared__ float wS[MAXD][EXPH];
    __shared__ float wmaskS[EXPH];
    __shared__ int Dcnt;
    int n = blockIdx.x;
    int t = threadIdx.x;
    int o0 = offs[n], o1 = offs[n + 1];
    int dg = o1 - o0;
    if (dg > MAXD) dg = MAXD;  // Poisson(16): P(deg>128) ~ 0
    if (t == 0) Dcnt = 0;
    if (t < dg) { dstS[t] = edst[o0 + t]; idS[t] = eid[o0 + t]; }
    __syncthreads();
    // deterministic order: sort by edge id (insertion sort, dg ~ 16)
    if (t == 0) {
        for (int i = 1; i < dg; i++) {
            int d = dstS[i], id = idS[i]; int j = i - 1;
            while (j >= 0 && idS[j] > id) { dstS[j + 1] = dstS[j]; idS[j + 1] = idS[j]; j--; }
            dstS[j + 1] = d; idS[j + 1] = id;
        }
    }
    __syncthreads();
    if (t < dg) {
        int live = 1;  // last write (max id) wins for duplicate (src,dst)
        for (int j = 0; j < dg; j++)
            if (dstS[j] == dstS[t] && idS[j] > idS[t]) live = 0;
        liveS[t] = live;
        if (live) atomicAdd(&Dcnt, 1);
    }
    for (int idx = t; idx < dg * EXPH; idx += 256) {
        int i = idx >> 4, e = idx & 15;
        aS[i][e] = aArr[(size_t)idS[i] * EXPH + e];
    }
    __syncthreads();
    int D = Dcnt;
    if (t < EXPH) {
        int e = t;
        float Me = Mbuf[e];
        float rmax = Me;
        for (int i = 0; i < dg; i++) if (liveS[i]) rmax = fmaxf(rmax, aS[i][e]);
        float wm = expf(Me - rmax);
        float denom = (float)(NN - D) * wm;
        for (int i = 0; i < dg; i++)
            if (liveS[i]) { float w = expf(aS[i][e] - rmax); wS[i][e] = w; denom += w; }
        for (int i = 0; i < dg; i++)
            if (liveS[i]) wS[i][e] = wS[i][e] / denom;
        wmaskS[e] = wm / denom;
    }
    __syncthreads();
    // out2[n][c] = vv[n][c] - wmask*colsum[c] + sum_live (wmask - w_i) * vv[dst_i][c]
    int c = t * 2;
    int e = c >> 5;
    float wm = wmaskS[e];
    const float2* vvn = (const float2*)(P + (size_t)n * PW + 512);
    const float2* cs2 = (const float2*)colsum;
    float2 v0 = vvn[t];
    float2 cv = cs2[t];
    float ax = v0.x - wm * cv.x;
    float ay = v0.y - wm * cv.y;
    for (int i = 0; i < dg; i++) {
        if (!liveS[i]) continue;
        float w = wm - wS[i][e];
        const float2* vr = (const float2*)(P + (size_t)dstS[i] * PW + 512);
        float2 vb = vr[t];
        ax += w * vb.x; ay += w * vb.y;
    }
    float2* o = (float2*)(out2 + (size_t)n * VDIM);
    o[t] = make_float2(ax, ay);
}

// ---------- final GEMM: C (2048x256) = out2 (2048x512) @ Wout^T (Wout 256x512) ----------
__global__ __launch_bounds__(256) void outgemm_kernel(
    const float* __restrict__ A, const float* __restrict__ W, float* __restrict__ C)
{
    __shared__ float As[16][64];
    __shared__ float Bs[16][64];
    int t = threadIdx.x;
    int rowT = blockIdx.x * 64;
    int colT = blockIdx.y * 64;
    int tm = t & 15, tn = t >> 4;
    float acc[4][4];
    #pragma unroll
    for (int i = 0; i < 4; i++)
        #pragma unroll
        for (int j = 0; j < 4; j++) acc[i][j] = 0.f;
    for (int k0 = 0; k0 < VDIM; k0 += 16) {
        int lr = t >> 2;
        int lk = (t & 3) * 4;
        float4 av = *(const float4*)(A + (size_t)(rowT + lr) * VDIM + k0 + lk);
        As[lk + 0][lr] = av.x; As[lk + 1][lr] = av.y;
        As[lk + 2][lr] = av.z; As[lk + 3][lr] = av.w;
        float4 bv = *(const float4*)(W + (size_t)(colT + lr) * VDIM + k0 + lk);
        Bs[lk + 0][lr] = bv.x; Bs[lk + 1][lr] = bv.y;
        Bs[lk + 2][lr] = bv.z; Bs[lk + 3][lr] = bv.w;
        __syncthreads();
        #pragma unroll
        for (int kk = 0; kk < 16; kk++) {
            float4 a4 = *(const float4*)&As[kk][tm * 4];
            float4 b4 = *(const float4*)&Bs[kk][tn * 4];
            float am[4] = {a4.x, a4.y, a4.z, a4.w};
            float bm[4] = {b4.x, b4.y, b4.z, b4.w};
            #pragma unroll
            for (int i = 0; i < 4; i++)
                #pragma unroll
                for (int j = 0; j < 4; j++) acc[i][j] += am[i] * bm[j];
        }
        __syncthreads();
    }
    #pragma unroll
    for (int i = 0; i < 4; i++) {
        int r = rowT + tm * 4 + i;
        #pragma unroll
        for (int j = 0; j < 4; j++)
            C[(size_t)r * DIMM + colT + tn * 4 + j] = acc[i][j];
    }
}

extern "C" void kernel_launch(void* const* d_in, const int* in_sizes, int n_in,
                              void* d_out, int out_size, void* d_ws, size_t ws_size,
                              hipStream_t stream) {
    const float* x     = (const float*)d_in[0];
    const float* edges = (const float*)d_in[1];
    const int*   ei32  = (const int*)d_in[2];
    const float* Wq    = (const float*)d_in[3];
    const float* Wk    = (const float*)d_in[4];
    const float* Wv    = (const float*)d_in[5];
    const float* Wev   = (const float*)d_in[6];
    const float* Wexp  = (const float*)d_in[7];
    const float* Wout  = (const float*)d_in[8];
    float* out = (float*)d_out;

    char* ws = (char*)d_ws;
    size_t off = 0;
    auto alloc = [&](size_t bytes) -> void* {
        void* p = ws + off;
        off = (off + bytes + 255) & ~(size_t)255;
        return p;
    };
    float* P      = (float*)alloc((size_t)NN * PW * 4);        // 8 MB
    float* out2   = (float*)alloc((size_t)NN * VDIM * 4);      // 4 MB
    float* aArr   = (float*)alloc((size_t)E_EDGES * EXPH * 4); // 2 MB
    float* colsum = (float*)alloc(VDIM * 4);
    float* Mbuf   = (float*)alloc(EXPH * 4);
    int* flag     = (int*)alloc(4);
    int* deg      = (int*)alloc(NN * 4);
    int* cursor   = (int*)alloc(NN * 4);
    int* offs     = (int*)alloc((NN + 1) * 4);
    int* edst     = (int*)alloc(E_EDGES * 4);
    int* eid      = (int*)alloc(E_EDGES * 4);
    (void)ws_size; (void)in_sizes; (void)n_in; (void)out_size;

    hipMemsetAsync(deg, 0, NN * 4, stream);
    hipMemsetAsync(cursor, 0, NN * 4, stream);

    detect_kernel<<<1, 256, 0, stream>>>(ei32, flag);
    proj_kernel<<<dim3(32, 16), 256, 0, stream>>>(x, edges, Wq, Wk, Wv, Wev, P);
    me_kernel<<<1, 64, 0, stream>>>(Wexp, Mbuf);
    colsum_kernel<<<2, 256, 0, stream>>>(P, colsum);
    edgea_kernel<<<E_EDGES / 32, 256, 0, stream>>>(ei32, flag, P, Wexp, aArr);
    hist_kernel<<<E_EDGES / 256, 256, 0, stream>>>(ei32, flag, deg);
    scan_kernel<<<1, 256, 0, stream>>>(deg, offs);
    fill_kernel<<<E_EDGES / 256, 256, 0, stream>>>(ei32, flag, offs, cursor, edst, eid);
    laplacian_kernel<<<NN, 256, 0, stream>>>(offs, edst, eid, aArr, Mbuf, colsum, P, out2);
    outgemm_kernel<<<dim3(32, 4), 256, 0, stream>>>(out2, Wout, out);
}

// Round 2
// 156.558 us; speedup vs baseline: 1.4619x; 1.4619x over previous
//
#include <hip/hip_runtime.h>

#define NN 2048
#define DIMM 256
#define HEADS 8
#define HEAD_DIM 32
#define EXPH 16
#define E_EDGES 32768
#define VDIM 512          // EXPH*HEAD_DIM
#define PW 1024           // P row width: [q 256 | k*scale 256 | vv 512]
#define SCALE_F 0.17677669529663687f
#define MASKV -1.0e9f
#define MAXD 128
#define CS_BLOCKS 128
#define CS_ROWS (NN / CS_BLOCKS)   // 16

// ---------- edge-index dtype detection (int32 vs int64) ----------
__global__ void detect_kernel(const int* __restrict__ ei32, int* __restrict__ flag) {
    __shared__ int nz;
    if (threadIdx.x == 0) nz = 0;
    __syncthreads();
    if (ei32[2 * threadIdx.x + 1] != 0) atomicAdd(&nz, 1);
    __syncthreads();
    if (threadIdx.x == 0) flag[0] = (nz == 0) ? 1 : 0;  // 1 => int64
}

__device__ __forceinline__ int load_edge(const int* __restrict__ ei32, int is64, int idx) {
    return is64 ? ei32[2 * idx] : ei32[idx];  // little-endian low word holds value (< 2^31)
}

// ---------- projections: P[n][0:256]=x@Wq^T ; [256:512]=x@Wk^T*SCALE ; [512:1024]=x@Wv^T+edges@Wev^T
__global__ __launch_bounds__(256) void proj_kernel(
    const float* __restrict__ x, const float* __restrict__ edges,
    const float* __restrict__ Wq, const float* __restrict__ Wk,
    const float* __restrict__ Wv, const float* __restrict__ Wev,
    float* __restrict__ P)
{
    __shared__ float As[16][64];
    __shared__ float Bs[16][64];
    int t = threadIdx.x;
    int rowT = blockIdx.x * 64;
    int jb = blockIdx.y;
    int colT = jb * 64;

    const float* W; int wbase; int nseg = 1;
    if (jb < 4)      { W = Wq; wbase = colT; }
    else if (jb < 8) { W = Wk; wbase = colT - 256; }
    else             { W = Wv; wbase = colT - 512; nseg = 2; }

    int tm = t & 15, tn = t >> 4;
    float acc[4][4];
    #pragma unroll
    for (int i = 0; i < 4; i++)
        #pragma unroll
        for (int j = 0; j < 4; j++) acc[i][j] = 0.f;

    for (int seg = 0; seg < nseg; ++seg) {
        const float* A  = (seg == 0) ? x : edges;
        const float* Wm = (seg == 0) ? W : Wev;
        for (int k0 = 0; k0 < DIMM; k0 += 16) {
            int lr = t >> 2;
            int lk = (t & 3) * 4;
            float4 av = *(const float4*)(A + (size_t)(rowT + lr) * DIMM + k0 + lk);
            As[lk + 0][lr] = av.x; As[lk + 1][lr] = av.y;
            As[lk + 2][lr] = av.z; As[lk + 3][lr] = av.w;
            float4 bv = *(const float4*)(Wm + (size_t)(wbase + lr) * DIMM + k0 + lk);
            Bs[lk + 0][lr] = bv.x; Bs[lk + 1][lr] = bv.y;
            Bs[lk + 2][lr] = bv.z; Bs[lk + 3][lr] = bv.w;
            __syncthreads();
            #pragma unroll
            for (int kk = 0; kk < 16; kk++) {
                float4 a4 = *(const float4*)&As[kk][tm * 4];
                float4 b4 = *(const float4*)&Bs[kk][tn * 4];
                float am[4] = {a4.x, a4.y, a4.z, a4.w};
                float bm[4] = {b4.x, b4.y, b4.z, b4.w};
                #pragma unroll
                for (int i = 0; i < 4; i++)
                    #pragma unroll
                    for (int j = 0; j < 4; j++) acc[i][j] += am[i] * bm[j];
            }
            __syncthreads();
        }
    }
    float sc = (jb >= 4 && jb < 8) ? SCALE_F : 1.0f;
    #pragma unroll
    for (int i = 0; i < 4; i++) {
        int r = rowT + tm * 4 + i;
        #pragma unroll
        for (int j = 0; j < 4; j++)
            P[(size_t)r * PW + colT + tn * 4 + j] = acc[i][j] * sc;
    }
}

// ---------- M_e = sum_h MASKV * Wexp[e,h] ----------
__global__ void me_kernel(const float* __restrict__ Wexp, float* __restrict__ M) {
    int e = threadIdx.x;
    if (e < EXPH) {
        float s = 0.f;
        for (int h = 0; h < HEADS; h++) s += MASKV * Wexp[e * HEADS + h];
        M[e] = s;
    }
}

// ---------- colsum stage 1: partial[b][c] = sum over 16 rows of vv[.][c] ----------
__global__ __launch_bounds__(256) void colsum1_kernel(const float* __restrict__ P, float* __restrict__ partial) {
    int b = blockIdx.x;
    int t = threadIdx.x;
    int r0 = b * CS_ROWS;
    #pragma unroll
    for (int cg = 0; cg < 2; cg++) {
        int c = cg * 256 + t;
        float s = 0.f;
        #pragma unroll
        for (int r = 0; r < CS_ROWS; r++)
            s += P[(size_t)(r0 + r) * PW + 512 + c];
        partial[(size_t)b * VDIM + c] = s;
    }
}

// ---------- colsum stage 2: colsum[c] = sum_b partial[b][c] ----------
__global__ __launch_bounds__(512) void colsum2_kernel(const float* __restrict__ partial, float* __restrict__ colsum) {
    int c = threadIdx.x;  // 0..511
    float s = 0.f;
    for (int b = 0; b < CS_BLOCKS; b++) s += partial[(size_t)b * VDIM + c];
    colsum[c] = s;
}

// ---------- per-edge expanded attention values a[p][e] ----------
__global__ __launch_bounds__(256) void edgea_kernel(
    const int* __restrict__ ei32, const int* __restrict__ flag,
    const float* __restrict__ P, const float* __restrict__ Wexp,
    float* __restrict__ aArr)
{
    __shared__ float ewS[32][8];
    __shared__ float WexpS[EXPH * HEADS];
    int t = threadIdx.x;
    if (t < EXPH * HEADS) WexpS[t] = Wexp[t];
    int is64 = flag[0];
    int pl = t >> 3;
    int h  = t & 7;
    int p  = blockIdx.x * 32 + pl;
    int src = load_edge(ei32, is64, p);
    int dst = load_edge(ei32, is64, E_EDGES + p);
    const float4* qr = (const float4*)(P + (size_t)src * PW + h * 32);
    const float4* kr = (const float4*)(P + (size_t)dst * PW + 256 + h * 32);
    float s = 0.f;
    #pragma unroll
    for (int i = 0; i < 8; i++) {
        float4 a = qr[i], b = kr[i];
        s += a.x * b.x + a.y * b.y + a.z * b.z + a.w * b.w;
    }
    ewS[pl][h] = s;
    __syncthreads();
    #pragma unroll
    for (int r = 0; r < 2; r++) {
        int idx = t + r * 256;
        int pe = idx >> 4, e = idx & 15;
        float a = 0.f;
        #pragma unroll
        for (int hh = 0; hh < HEADS; hh++) a += ewS[pe][hh] * WexpS[e * HEADS + hh];
        aArr[(size_t)(blockIdx.x * 32 + pe) * EXPH + e] = a;
    }
}

// ---------- CSR build ----------
__global__ void hist_kernel(const int* __restrict__ ei32, const int* __restrict__ flag, int* __restrict__ deg) {
    int p = blockIdx.x * 256 + threadIdx.x;
    int is64 = flag[0];
    if (p < E_EDGES) atomicAdd(&deg[load_edge(ei32, is64, p)], 1);
}

__global__ __launch_bounds__(256) void scan_kernel(const int* __restrict__ deg, int* __restrict__ offs) {
    __shared__ int part[256];
    __shared__ int pref[257];
    int t = threadIdx.x;
    int base = t * 8;
    int s = 0;
    for (int i = 0; i < 8; i++) s += deg[base + i];
    part[t] = s;
    __syncthreads();
    if (t == 0) {
        int r = 0;
        for (int i = 0; i < 256; i++) { pref[i] = r; r += part[i]; }
        pref[256] = r;
    }
    __syncthreads();
    int run = pref[t];
    for (int i = 0; i < 8; i++) { offs[base + i] = run; run += deg[base + i]; }
    if (t == 0) offs[NN] = pref[256];
}

__global__ void fill_kernel(const int* __restrict__ ei32, const int* __restrict__ flag,
                            const int* __restrict__ offs, int* __restrict__ cursor,
                            int* __restrict__ edst, int* __restrict__ eid) {
    int p = blockIdx.x * 256 + threadIdx.x;
    int is64 = flag[0];
    if (p < E_EDGES) {
        int s = load_edge(ei32, is64, p);
        int pos = offs[s] + atomicAdd(&cursor[s], 1);
        edst[pos] = load_edge(ei32, is64, E_EDGES + p);
        eid[pos]  = p;
    }
}

// ---------- main: per-node softmax + Laplacian apply ----------
__global__ __launch_bounds__(256) void laplacian_kernel(
    const int* __restrict__ offs, const int* __restrict__ edst, const int* __restrict__ eid,
    const float* __restrict__ aArr, const float* __restrict__ Mbuf,
    const float* __restrict__ colsum, const float* __restrict__ P,
    float* __restrict__ out2)
{
    __shared__ int dstS[MAXD], idS[MAXD], liveS[MAXD];
    __shared__ float aS[MAXD][EXPH];
    __shared__ float wS[MAXD][EXPH];
    __shared__ float wmaskS[EXPH];
    __shared__ int Dcnt;
    int n = blockIdx.x;
    int t = threadIdx.x;
    int o0 = offs[n], o1 = offs[n + 1];
    int dg = o1 - o0;
    if (dg > MAXD) dg = MAXD;  // Poisson(16): P(deg>128) ~ 0
    if (t == 0) Dcnt = 0;
    if (t < dg) { dstS[t] = edst[o0 + t]; idS[t] = eid[o0 + t]; }
    __syncthreads();
    // deterministic order: sort by edge id (insertion sort, dg ~ 16)
    if (t == 0) {
        for (int i = 1; i < dg; i++) {
            int d = dstS[i], id = idS[i]; int j = i - 1;
            while (j >= 0 && idS[j] > id) { dstS[j + 1] = dstS[j]; idS[j + 1] = idS[j]; j--; }
            dstS[j + 1] = d; idS[j + 1] = id;
        }
    }
    __syncthreads();
    if (t < dg) {
        int live = 1;  // last write (max id) wins for duplicate (src,dst)
        for (int j = 0; j < dg; j++)
            if (dstS[j] == dstS[t] && idS[j] > idS[t]) live = 0;
        liveS[t] = live;
        if (live) atomicAdd(&Dcnt, 1);
    }
    for (int idx = t; idx < dg * EXPH; idx += 256) {
        int i = idx >> 4, e = idx & 15;
        aS[i][e] = aArr[(size_t)idS[i] * EXPH + e];
    }
    __syncthreads();
    int D = Dcnt;
    if (t < EXPH) {
        int e = t;
        float Me = Mbuf[e];
        float rmax = Me;
        for (int i = 0; i < dg; i++) if (liveS[i]) rmax = fmaxf(rmax, aS[i][e]);
        float wm = expf(Me - rmax);
        float denom = (float)(NN - D) * wm;
        for (int i = 0; i < dg; i++)
            if (liveS[i]) { float w = expf(aS[i][e] - rmax); wS[i][e] = w; denom += w; }
        for (int i = 0; i < dg; i++)
            if (liveS[i]) wS[i][e] = wS[i][e] / denom;
        wmaskS[e] = wm / denom;
    }
    __syncthreads();
    // out2[n][c] = vv[n][c] - wmask*colsum[c] + sum_live (wmask - w_i) * vv[dst_i][c]
    int c = t * 2;
    int e = c >> 5;
    float wm = wmaskS[e];
    const float2* vvn = (const float2*)(P + (size_t)n * PW + 512);
    const float2* cs2 = (const float2*)colsum;
    float2 v0 = vvn[t];
    float2 cv = cs2[t];
    float ax = v0.x - wm * cv.x;
    float ay = v0.y - wm * cv.y;
    for (int i = 0; i < dg; i++) {
        if (!liveS[i]) continue;
        float w = wm - wS[i][e];
        const float2* vr = (const float2*)(P + (size_t)dstS[i] * PW + 512);
        float2 vb = vr[t];
        ax += w * vb.x; ay += w * vb.y;
    }
    float2* o = (float2*)(out2 + (size_t)n * VDIM);
    o[t] = make_float2(ax, ay);
}

// ---------- final GEMM: C (2048x256) = out2 (2048x512) @ Wout^T (Wout 256x512) ----------
__global__ __launch_bounds__(256) void outgemm_kernel(
    const float* __restrict__ A, const float* __restrict__ W, float* __restrict__ C)
{
    __shared__ float As[16][64];
    __shared__ float Bs[16][64];
    int t = threadIdx.x;
    int rowT = blockIdx.x * 64;
    int colT = blockIdx.y * 64;
    int tm = t & 15, tn = t >> 4;
    float acc[4][4];
    #pragma unroll
    for (int i = 0; i < 4; i++)
        #pragma unroll
        for (int j = 0; j < 4; j++) acc[i][j] = 0.f;
    for (int k0 = 0; k0 < VDIM; k0 += 16) {
        int lr = t >> 2;
        int lk = (t & 3) * 4;
        float4 av = *(const float4*)(A + (size_t)(rowT + lr) * VDIM + k0 + lk);
        As[lk + 0][lr] = av.x; As[lk + 1][lr] = av.y;
        As[lk + 2][lr] = av.z; As[lk + 3][lr] = av.w;
        float4 bv = *(const float4*)(W + (size_t)(colT + lr) * VDIM + k0 + lk);
        Bs[lk + 0][lr] = bv.x; Bs[lk + 1][lr] = bv.y;
        Bs[lk + 2][lr] = bv.z; Bs[lk + 3][lr] = bv.w;
        __syncthreads();
        #pragma unroll
        for (int kk = 0; kk < 16; kk++) {
            float4 a4 = *(const float4*)&As[kk][tm * 4];
            float4 b4 = *(const float4*)&Bs[kk][tn * 4];
            float am[4] = {a4.x, a4.y, a4.z, a4.w};
            float bm[4] = {b4.x, b4.y, b4.z, b4.w};
            #pragma unroll
            for (int i = 0; i < 4; i++)
                #pragma unroll
                for (int j = 0; j < 4; j++) acc[i][j] += am[i] * bm[j];
        }
        __syncthreads();
    }
    #pragma unroll
    for (int i = 0; i < 4; i++) {
        int r = rowT + tm * 4 + i;
        #pragma unroll
        for (int j = 0; j < 4; j++)
            C[(size_t)r * DIMM + colT + tn * 4 + j] = acc[i][j];
    }
}

extern "C" void kernel_launch(void* const* d_in, const int* in_sizes, int n_in,
                              void* d_out, int out_size, void* d_ws, size_t ws_size,
                              hipStream_t stream) {
    const float* x     = (const float*)d_in[0];
    const float* edges = (const float*)d_in[1];
    const int*   ei32  = (const int*)d_in[2];
    const float* Wq    = (const float*)d_in[3];
    const float* Wk    = (const float*)d_in[4];
    const float* Wv    = (const float*)d_in[5];
    const float* Wev   = (const float*)d_in[6];
    const float* Wexp  = (const float*)d_in[7];
    const float* Wout  = (const float*)d_in[8];
    float* out = (float*)d_out;

    char* ws = (char*)d_ws;
    size_t off = 0;
    auto alloc = [&](size_t bytes) -> void* {
        void* p = ws + off;
        off = (off + bytes + 255) & ~(size_t)255;
        return p;
    };
    float* P       = (float*)alloc((size_t)NN * PW * 4);        // 8 MB
    float* out2    = (float*)alloc((size_t)NN * VDIM * 4);      // 4 MB
    float* aArr    = (float*)alloc((size_t)E_EDGES * EXPH * 4); // 2 MB
    float* partial = (float*)alloc((size_t)CS_BLOCKS * VDIM * 4); // 256 KB
    float* colsum  = (float*)alloc(VDIM * 4);
    float* Mbuf    = (float*)alloc(EXPH * 4);
    int* flag      = (int*)alloc(4);
    int* deg       = (int*)alloc(NN * 4);
    int* cursor    = (int*)alloc(NN * 4);
    int* offs      = (int*)alloc((NN + 1) * 4);
    int* edst      = (int*)alloc(E_EDGES * 4);
    int* eid       = (int*)alloc(E_EDGES * 4);
    (void)ws_size; (void)in_sizes; (void)n_in; (void)out_size;

    hipMemsetAsync(deg, 0, NN * 4, stream);
    hipMemsetAsync(cursor, 0, NN * 4, stream);

    detect_kernel<<<1, 256, 0, stream>>>(ei32, flag);
    proj_kernel<<<dim3(32, 16), 256, 0, stream>>>(x, edges, Wq, Wk, Wv, Wev, P);
    me_kernel<<<1, 64, 0, stream>>>(Wexp, Mbuf);
    colsum1_kernel<<<CS_BLOCKS, 256, 0, stream>>>(P, partial);
    colsum2_kernel<<<1, 512, 0, stream>>>(partial, colsum);
    edgea_kernel<<<E_EDGES / 32, 256, 0, stream>>>(ei32, flag, P, Wexp, aArr);
    hist_kernel<<<E_EDGES / 256, 256, 0, stream>>>(ei32, flag, deg);
    scan_kernel<<<1, 256, 0, stream>>>(deg, offs);
    fill_kernel<<<E_EDGES / 256, 256, 0, stream>>>(ei32, flag, offs, cursor, edst, eid);
    laplacian_kernel<<<NN, 256, 0, stream>>>(offs, edst, eid, aArr, Mbuf, colsum, P, out2);
    outgemm_kernel<<<dim3(32, 4), 256, 0, stream>>>(out2, Wout, out);
}

// Round 3
// 127.710 us; speedup vs baseline: 1.7922x; 1.2259x over previous
//
#include <hip/hip_runtime.h>

#define NN 2048
#define DIMM 256
#define HEADS 8
#define HEAD_DIM 32
#define EXPH 16
#define E_EDGES 32768
#define VDIM 512          // EXPH*HEAD_DIM
#define PW 1024           // P row width: [q 256 | k*scale 256 | vv 512]
#define SCALE_F 0.17677669529663687f
#define MASKV -1.0e9f
#define MAXD 128
#define CS_BLOCKS 128
#define CS_ROWS (NN / CS_BLOCKS)   // 16

// ---------- edge-index dtype detection + M_e precompute (merged) ----------
__global__ void detect_me_kernel(const int* __restrict__ ei32, const float* __restrict__ Wexp,
                                 int* __restrict__ flag, float* __restrict__ M) {
    __shared__ int nz;
    if (threadIdx.x == 0) nz = 0;
    __syncthreads();
    if (ei32[2 * threadIdx.x + 1] != 0) atomicAdd(&nz, 1);
    __syncthreads();
    if (threadIdx.x == 0) flag[0] = (nz == 0) ? 1 : 0;  // 1 => int64
    if (threadIdx.x < EXPH) {
        float s = 0.f;
        for (int h = 0; h < HEADS; h++) s += MASKV * Wexp[threadIdx.x * HEADS + h];
        M[threadIdx.x] = s;
    }
}

__device__ __forceinline__ int load_edge(const int* __restrict__ ei32, int is64, int idx) {
    return is64 ? ei32[2 * idx] : ei32[idx];  // little-endian low word holds value (< 2^31)
}

// ---------- projections: P[n][0:256]=x@Wq^T ; [256:512]=x@Wk^T*SCALE ; [512:1024]=x@Wv^T+edges@Wev^T
__global__ __launch_bounds__(256) void proj_kernel(
    const float* __restrict__ x, const float* __restrict__ edges,
    const float* __restrict__ Wq, const float* __restrict__ Wk,
    const float* __restrict__ Wv, const float* __restrict__ Wev,
    float* __restrict__ P)
{
    __shared__ float As[16][64];
    __shared__ float Bs[16][64];
    int t = threadIdx.x;
    int rowT = blockIdx.x * 64;
    int jb = blockIdx.y;
    int colT = jb * 64;

    const float* W; int wbase; int nseg = 1;
    if (jb < 4)      { W = Wq; wbase = colT; }
    else if (jb < 8) { W = Wk; wbase = colT - 256; }
    else             { W = Wv; wbase = colT - 512; nseg = 2; }

    int tm = t & 15, tn = t >> 4;
    float acc[4][4];
    #pragma unroll
    for (int i = 0; i < 4; i++)
        #pragma unroll
        for (int j = 0; j < 4; j++) acc[i][j] = 0.f;

    for (int seg = 0; seg < nseg; ++seg) {
        const float* A  = (seg == 0) ? x : edges;
        const float* Wm = (seg == 0) ? W : Wev;
        for (int k0 = 0; k0 < DIMM; k0 += 16) {
            int lr = t >> 2;
            int lk = (t & 3) * 4;
            float4 av = *(const float4*)(A + (size_t)(rowT + lr) * DIMM + k0 + lk);
            As[lk + 0][lr] = av.x; As[lk + 1][lr] = av.y;
            As[lk + 2][lr] = av.z; As[lk + 3][lr] = av.w;
            float4 bv = *(const float4*)(Wm + (size_t)(wbase + lr) * DIMM + k0 + lk);
            Bs[lk + 0][lr] = bv.x; Bs[lk + 1][lr] = bv.y;
            Bs[lk + 2][lr] = bv.z; Bs[lk + 3][lr] = bv.w;
            __syncthreads();
            #pragma unroll
            for (int kk = 0; kk < 16; kk++) {
                float4 a4 = *(const float4*)&As[kk][tm * 4];
                float4 b4 = *(const float4*)&Bs[kk][tn * 4];
                float am[4] = {a4.x, a4.y, a4.z, a4.w};
                float bm[4] = {b4.x, b4.y, b4.z, b4.w};
                #pragma unroll
                for (int i = 0; i < 4; i++)
                    #pragma unroll
                    for (int j = 0; j < 4; j++) acc[i][j] += am[i] * bm[j];
            }
            __syncthreads();
        }
    }
    float sc = (jb >= 4 && jb < 8) ? SCALE_F : 1.0f;
    #pragma unroll
    for (int i = 0; i < 4; i++) {
        int r = rowT + tm * 4 + i;
        #pragma unroll
        for (int j = 0; j < 4; j++)
            P[(size_t)r * PW + colT + tn * 4 + j] = acc[i][j] * sc;
    }
}

// ---------- colsum stage 1: partial[b][c] = sum over 16 rows of vv[.][c] ----------
__global__ __launch_bounds__(256) void colsum1_kernel(const float* __restrict__ P, float* __restrict__ partial) {
    int b = blockIdx.x;
    int t = threadIdx.x;
    int r0 = b * CS_ROWS;
    #pragma unroll
    for (int cg = 0; cg < 2; cg++) {
        int c = cg * 256 + t;
        float s = 0.f;
        #pragma unroll
        for (int r = 0; r < CS_ROWS; r++)
            s += P[(size_t)(r0 + r) * PW + 512 + c];
        partial[(size_t)b * VDIM + c] = s;
    }
}

// ---------- colsum stage 2: colsum[c] = sum_b partial[b][c] ----------
__global__ __launch_bounds__(512) void colsum2_kernel(const float* __restrict__ partial, float* __restrict__ colsum) {
    int c = threadIdx.x;  // 0..511
    float s = 0.f;
    for (int b = 0; b < CS_BLOCKS; b++) s += partial[(size_t)b * VDIM + c];
    colsum[c] = s;
}

// ---------- per-edge expanded attention values a[p][e] ----------
__global__ __launch_bounds__(256) void edgea_kernel(
    const int* __restrict__ ei32, const int* __restrict__ flag,
    const float* __restrict__ P, const float* __restrict__ Wexp,
    float* __restrict__ aArr)
{
    __shared__ float ewS[32][8];
    __shared__ float WexpS[EXPH * HEADS];
    int t = threadIdx.x;
    if (t < EXPH * HEADS) WexpS[t] = Wexp[t];
    int is64 = flag[0];
    int pl = t >> 3;
    int h  = t & 7;
    int p  = blockIdx.x * 32 + pl;
    int src = load_edge(ei32, is64, p);
    int dst = load_edge(ei32, is64, E_EDGES + p);
    const float4* qr = (const float4*)(P + (size_t)src * PW + h * 32);
    const float4* kr = (const float4*)(P + (size_t)dst * PW + 256 + h * 32);
    float s = 0.f;
    #pragma unroll
    for (int i = 0; i < 8; i++) {
        float4 a = qr[i], b = kr[i];
        s += a.x * b.x + a.y * b.y + a.z * b.z + a.w * b.w;
    }
    ewS[pl][h] = s;
    __syncthreads();
    #pragma unroll
    for (int r = 0; r < 2; r++) {
        int idx = t + r * 256;
        int pe = idx >> 4, e = idx & 15;
        float a = 0.f;
        #pragma unroll
        for (int hh = 0; hh < HEADS; hh++) a += ewS[pe][hh] * WexpS[e * HEADS + hh];
        aArr[(size_t)(blockIdx.x * 32 + pe) * EXPH + e] = a;
    }
}

// ---------- CSR build ----------
__global__ void hist_kernel(const int* __restrict__ ei32, const int* __restrict__ flag, int* __restrict__ deg) {
    int p = blockIdx.x * 256 + threadIdx.x;
    int is64 = flag[0];
    if (p < E_EDGES) atomicAdd(&deg[load_edge(ei32, is64, p)], 1);
}

__global__ __launch_bounds__(256) void scan_kernel(const int* __restrict__ deg, int* __restrict__ offs) {
    __shared__ int part[256];
    __shared__ int pref[257];
    int t = threadIdx.x;
    int base = t * 8;
    int s = 0;
    for (int i = 0; i < 8; i++) s += deg[base + i];
    part[t] = s;
    __syncthreads();
    if (t == 0) {
        int r = 0;
        for (int i = 0; i < 256; i++) { pref[i] = r; r += part[i]; }
        pref[256] = r;
    }
    __syncthreads();
    int run = pref[t];
    for (int i = 0; i < 8; i++) { offs[base + i] = run; run += deg[base + i]; }
    if (t == 0) offs[NN] = pref[256];
}

__global__ void fill_kernel(const int* __restrict__ ei32, const int* __restrict__ flag,
                            const int* __restrict__ offs, int* __restrict__ cursor,
                            int* __restrict__ edst, int* __restrict__ eid) {
    int p = blockIdx.x * 256 + threadIdx.x;
    int is64 = flag[0];
    if (p < E_EDGES) {
        int s = load_edge(ei32, is64, p);
        int pos = offs[s] + atomicAdd(&cursor[s], 1);
        edst[pos] = load_edge(ei32, is64, E_EDGES + p);
        eid[pos]  = p;
    }
}

// ---------- main: per-node softmax + Laplacian apply (fully parallel inside block) ----------
__global__ __launch_bounds__(256) void laplacian_kernel(
    const int* __restrict__ offs, const int* __restrict__ edst, const int* __restrict__ eid,
    const float* __restrict__ aArr, const float* __restrict__ Mbuf,
    const float* __restrict__ colsum, const float* __restrict__ P,
    float* __restrict__ out2)
{
    __shared__ int dstS[MAXD], idS[MAXD];
    __shared__ int dst2[MAXD], id2[MAXD], liveS[MAXD];
    __shared__ float aS[MAXD][EXPH];
    __shared__ float wS[MAXD][EXPH];
    __shared__ float rmaxS[EXPH], wmES[EXPH], denomS[EXPH], wmaskS[EXPH];
    __shared__ int Dcnt;
    int n = blockIdx.x;
    int t = threadIdx.x;
    int o0 = offs[n], o1 = offs[n + 1];
    int dg = o1 - o0;
    if (dg > MAXD) dg = MAXD;  // Poisson(16): P(deg>128) ~ 0
    if (t == 0) Dcnt = 0;
    if (t < dg) { dstS[t] = edst[o0 + t]; idS[t] = eid[o0 + t]; }
    __syncthreads();
    // parallel rank sort by edge id (ids unique -> rank is a permutation)
    if (t < dg) {
        int id = idS[t], d = dstS[t];
        int rank = 0;
        for (int j = 0; j < dg; j++) rank += (idS[j] < id) ? 1 : 0;
        dst2[rank] = d; id2[rank] = id;
    }
    __syncthreads();
    // dedup: last write (max id) wins => live iff no later (higher-rank) duplicate dst
    if (t < dg) {
        int d = dst2[t], live = 1;
        for (int j = t + 1; j < dg; j++)
            if (dst2[j] == d) { live = 0; break; }
        liveS[t] = live;
        if (live) atomicAdd(&Dcnt, 1);
    }
    // gather edge attention values in sorted order
    for (int idx = t; idx < dg * EXPH; idx += 256) {
        int i = idx >> 4, e = idx & 15;
        aS[i][e] = aArr[(size_t)id2[i] * EXPH + e];
    }
    __syncthreads();
    // row max per e (16 lanes, short pipelined loop)
    if (t < EXPH) {
        int e = t;
        float Me = Mbuf[e];
        float rmax = Me;
        for (int i = 0; i < dg; i++) if (liveS[i]) rmax = fmaxf(rmax, aS[i][e]);
        rmaxS[e] = rmax;
        wmES[e] = expf(Me - rmax);
    }
    __syncthreads();
    // all exps in parallel (256 lanes)
    for (int idx = t; idx < dg * EXPH; idx += 256) {
        int i = idx >> 4, e = idx & 15;
        wS[i][e] = liveS[i] ? expf(aS[i][e] - rmaxS[e]) : 0.f;
    }
    __syncthreads();
    int D = Dcnt;
    // denominator per e, deterministic sorted order
    if (t < EXPH) {
        int e = t;
        float denom = (float)(NN - D) * wmES[e];
        for (int i = 0; i < dg; i++) denom += wS[i][e];
        denomS[e] = denom;
        wmaskS[e] = wmES[e] / denom;
    }
    __syncthreads();
    // normalize in parallel
    for (int idx = t; idx < dg * EXPH; idx += 256) {
        int i = idx >> 4, e = idx & 15;
        wS[i][e] = wS[i][e] / denomS[e];
    }
    __syncthreads();
    // out2[n][c] = vv[n][c] - wmask*colsum[c] + sum_live (wmask - w_i) * vv[dst_i][c]
    int e = t >> 4;
    float wm = wmaskS[e];
    const float2* vvn = (const float2*)(P + (size_t)n * PW + 512);
    const float2* cs2 = (const float2*)colsum;
    float2 v0 = vvn[t];
    float2 cv = cs2[t];
    float ax = v0.x - wm * cv.x;
    float ay = v0.y - wm * cv.y;
    for (int i = 0; i < dg; i++) {
        if (!liveS[i]) continue;
        float w = wm - wS[i][e];
        const float2* vr = (const float2*)(P + (size_t)dst2[i] * PW + 512);
        float2 vb = vr[t];
        ax += w * vb.x; ay += w * vb.y;
    }
    float2* o = (float2*)(out2 + (size_t)n * VDIM);
    o[t] = make_float2(ax, ay);
}

// ---------- final GEMM: C (2048x256) = out2 (2048x512) @ Wout^T (Wout 256x512) ----------
__global__ __launch_bounds__(256) void outgemm_kernel(
    const float* __restrict__ A, const float* __restrict__ W, float* __restrict__ C)
{
    __shared__ float As[16][64];
    __shared__ float Bs[16][64];
    int t = threadIdx.x;
    int rowT = blockIdx.x * 64;
    int colT = blockIdx.y * 64;
    int tm = t & 15, tn = t >> 4;
    float acc[4][4];
    #pragma unroll
    for (int i = 0; i < 4; i++)
        #pragma unroll
        for (int j = 0; j < 4; j++) acc[i][j] = 0.f;
    for (int k0 = 0; k0 < VDIM; k0 += 16) {
        int lr = t >> 2;
        int lk = (t & 3) * 4;
        float4 av = *(const float4*)(A + (size_t)(rowT + lr) * VDIM + k0 + lk);
        As[lk + 0][lr] = av.x; As[lk + 1][lr] = av.y;
        As[lk + 2][lr] = av.z; As[lk + 3][lr] = av.w;
        float4 bv = *(const float4*)(W + (size_t)(colT + lr) * VDIM + k0 + lk);
        Bs[lk + 0][lr] = bv.x; Bs[lk + 1][lr] = bv.y;
        Bs[lk + 2][lr] = bv.z; Bs[lk + 3][lr] = bv.w;
        __syncthreads();
        #pragma unroll
        for (int kk = 0; kk < 16; kk++) {
            float4 a4 = *(const float4*)&As[kk][tm * 4];
            float4 b4 = *(const float4*)&Bs[kk][tn * 4];
            float am[4] = {a4.x, a4.y, a4.z, a4.w};
            float bm[4] = {b4.x, b4.y, b4.z, b4.w};
            #pragma unroll
            for (int i = 0; i < 4; i++)
                #pragma unroll
                for (int j = 0; j < 4; j++) acc[i][j] += am[i] * bm[j];
        }
        __syncthreads();
    }
    #pragma unroll
    for (int i = 0; i < 4; i++) {
        int r = rowT + tm * 4 + i;
        #pragma unroll
        for (int j = 0; j < 4; j++)
            C[(size_t)r * DIMM + colT + tn * 4 + j] = acc[i][j];
    }
}

extern "C" void kernel_launch(void* const* d_in, const int* in_sizes, int n_in,
                              void* d_out, int out_size, void* d_ws, size_t ws_size,
                              hipStream_t stream) {
    const float* x     = (const float*)d_in[0];
    const float* edges = (const float*)d_in[1];
    const int*   ei32  = (const int*)d_in[2];
    const float* Wq    = (const float*)d_in[3];
    const float* Wk    = (const float*)d_in[4];
    const float* Wv    = (const float*)d_in[5];
    const float* Wev   = (const float*)d_in[6];
    const float* Wexp  = (const float*)d_in[7];
    const float* Wout  = (const float*)d_in[8];
    float* out = (float*)d_out;

    char* ws = (char*)d_ws;
    size_t off = 0;
    auto alloc = [&](size_t bytes) -> void* {
        void* p = ws + off;
        off = (off + bytes + 255) & ~(size_t)255;
        return p;
    };
    float* P       = (float*)alloc((size_t)NN * PW * 4);        // 8 MB
    float* out2    = (float*)alloc((size_t)NN * VDIM * 4);      // 4 MB
    float* aArr    = (float*)alloc((size_t)E_EDGES * EXPH * 4); // 2 MB
    float* partial = (float*)alloc((size_t)CS_BLOCKS * VDIM * 4); // 256 KB
    float* colsum  = (float*)alloc(VDIM * 4);
    float* Mbuf    = (float*)alloc(EXPH * 4);
    int* flag      = (int*)alloc(4);
    int* deg       = (int*)alloc(NN * 4);
    int* cursor    = (int*)alloc(NN * 4);
    int* offs      = (int*)alloc((NN + 1) * 4);
    int* edst      = (int*)alloc(E_EDGES * 4);
    int* eid       = (int*)alloc(E_EDGES * 4);
    (void)ws_size; (void)in_sizes; (void)n_in; (void)out_size;

    hipMemsetAsync(deg, 0, NN * 4, stream);
    hipMemsetAsync(cursor, 0, NN * 4, stream);

    detect_me_kernel<<<1, 256, 0, stream>>>(ei32, Wexp, flag, Mbuf);
    proj_kernel<<<dim3(32, 16), 256, 0, stream>>>(x, edges, Wq, Wk, Wv, Wev, P);
    colsum1_kernel<<<CS_BLOCKS, 256, 0, stream>>>(P, partial);
    colsum2_kernel<<<1, 512, 0, stream>>>(partial, colsum);
    edgea_kernel<<<E_EDGES / 32, 256, 0, stream>>>(ei32, flag, P, Wexp, aArr);
    hist_kernel<<<E_EDGES / 256, 256, 0, stream>>>(ei32, flag, deg);
    scan_kernel<<<1, 256, 0, stream>>>(deg, offs);
    fill_kernel<<<E_EDGES / 256, 256, 0, stream>>>(ei32, flag, offs, cursor, edst, eid);
    laplacian_kernel<<<NN, 256, 0, stream>>>(offs, edst, eid, aArr, Mbuf, colsum, P, out2);
    outgemm_kernel<<<dim3(32, 4), 256, 0, stream>>>(out2, Wout, out);
}